// Round 1
// baseline (5655.030 us; speedup 1.0000x reference)
//
#include <hip/hip_runtime.h>

// ---------------------------------------------------------------------------
// BiLSTM-CRF fused pipeline for MI355X (gfx950)
// B=64, S=512, V=50000, E=300, H=256 (H2=512), T=48
// Phases:
//   k_prep_*   : weight repack (bf16, transposed/packed layouts), bias fold, zero out
//   k_gather   : x = emb[token_ids]  -> bf16, K padded 300->320
//   k_gemm     : xproj = x @ [W_ih_f;W_ih_b]^T + bias   (bf16 MFMA, 128x128 tile)
//   k_rec      : 128 blocks = (batch x dir); sequential 512 steps; h in LDS, c in regs
//   k_lin      : logits = [h_f,h_b] @ W_lin^T + b_lin   (W staged bf16 in LDS)
//   k_crf      : per-chain wave, lane=tag; softmax fused; log2-domain forward scan
// ---------------------------------------------------------------------------

using short8 = __attribute__((ext_vector_type(8))) short;
using f32x4  = __attribute__((ext_vector_type(4))) float;
typedef unsigned int  uint;
typedef unsigned short ushort;

#define BATCH 64
#define SEQ   512
#define EMB   300
#define KPAD  320
#define HID   256
#define NTAG  48
#define NTOK  (BATCH*SEQ)          // 32768
#define T2STRIDE 60                // padded row stride for T2T (floats), 16B-aligned rows

__device__ __forceinline__ float bf2f(ushort u) { return __uint_as_float(((uint)u) << 16); }
__device__ __forceinline__ ushort f2bf(float f) {
  uint u = __float_as_uint(f);
  return (ushort)((u + 0x7fffu + ((u >> 16) & 1u)) >> 16);   // RNE
}
__device__ __forceinline__ uint pk2(float a, float b) {
  return (uint)f2bf(a) | ((uint)f2bf(b) << 16);
}
__device__ __forceinline__ float blo(uint u) { return __uint_as_float(u << 16); }
__device__ __forceinline__ float bhi(uint u) { return __uint_as_float(u & 0xffff0000u); }

// ---------------------------------------------------------------- prep kernels
__global__ void k_prep_wb(const float* __restrict__ wihf, const float* __restrict__ wihb,
                          ushort* __restrict__ wb) {
  int n = blockIdx.x;            // 0..2047
  int k = threadIdx.x;           // 0..319
  float v = 0.f;
  if (k < EMB) v = (n < 1024) ? wihf[n * EMB + k] : wihb[(n - 1024) * EMB + k];
  wb[n * KPAD + k] = f2bf(v);
}

__global__ void k_prep_whh(const float* __restrict__ whhf, const float* __restrict__ whhb,
                           uint4* __restrict__ whh8) {
  int blk = blockIdx.x;          // 0..63
  int dir = blk >> 5, k8 = blk & 31;
  const float* ws = dir ? whhb : whhf;   // (1024, 256) row-major
  for (int q = 0; q < 4; ++q) {
    int n = q * 256 + threadIdx.x;       // 0..1023
    const float* wr = ws + (size_t)n * HID + k8 * 8;
    uint4 o;
    o.x = pk2(wr[0], wr[1]); o.y = pk2(wr[2], wr[3]);
    o.z = pk2(wr[4], wr[5]); o.w = pk2(wr[6], wr[7]);
    whh8[((size_t)dir * 32 + k8) * 1024 + n] = o;
  }
}

__global__ void k_prep_wlt(const float* __restrict__ wlin, ushort* __restrict__ wltb) {
  int idx = blockIdx.x * 256 + threadIdx.x;   // < 32768
  int k = idx >> 6, j = idx & 63;
  wltb[idx] = f2bf((j < NTAG) ? wlin[j * 512 + k] : 0.f);
}

__global__ void k_prep_small(const float* __restrict__ bihf, const float* __restrict__ bhhf,
                             const float* __restrict__ bihb, const float* __restrict__ bhhb,
                             const float* __restrict__ trans,
                             float* __restrict__ bias, float* __restrict__ T2Tg,
                             float* __restrict__ cm2g, float* __restrict__ out) {
  int tid = threadIdx.x;
  if (tid == 0) out[0] = 0.f;
  for (int i = tid; i < 2048; i += 256)
    bias[i] = (i < 1024) ? (bihf[i] + bhhf[i]) : (bihb[i - 1024] + bhhb[i - 1024]);
  if (tid < NTAG) {
    const float L2E = 1.4426950408889634f;
    float cm = -3.0e38f;
    for (int i = 0; i < NTAG; ++i) cm = fmaxf(cm, trans[i * NTAG + tid] * L2E);
    cm2g[tid] = cm;
    for (int i = 0; i < NTAG; ++i)
      T2Tg[tid * T2STRIDE + i] = trans[i * NTAG + tid] * L2E - cm;
  }
}

// ---------------------------------------------------------------- gather
__global__ __launch_bounds__(256) void k_gather(const int* __restrict__ tok,
                                                const float* __restrict__ emb,
                                                ushort* __restrict__ xb) {
  int r = blockIdx.x * 4 + (threadIdx.x >> 6);   // token row, < 32768
  int l = threadIdx.x & 63;
  int t = tok[r];
  const float* e = emb + (size_t)t * EMB;
  ushort* xr = xb + (size_t)r * KPAD;
#pragma unroll
  for (int q = 0; q < 5; ++q) {
    int k = l + q * 64;
    xr[k] = f2bf((k < EMB) ? e[k] : 0.f);
  }
}

// ---------------------------------------------------------------- input-proj GEMM
// C[m,n] = sum_k xb[m,k]*wb[n,k] + bias[n]  -> bf16 xproj (32768 x 2048)
__global__ __launch_bounds__(256) void k_gemm(const ushort* __restrict__ xb,
                                              const ushort* __restrict__ wb,
                                              const float* __restrict__ bias,
                                              ushort* __restrict__ xproj) {
  __shared__ __align__(16) ushort Asm[128 * 64];
  __shared__ __align__(16) ushort Bsm[128 * 64];
  const int tid = threadIdx.x;
  const int w = tid >> 6, l = tid & 63;
  const int m0 = blockIdx.y * 128, n0 = blockIdx.x * 128;
  const int wr = (w >> 1) * 64, wc = (w & 1) * 64;
  f32x4 acc[4][4] = {};

  for (int kt = 0; kt < 5; ++kt) {
    const int k0 = kt * 64;
    short8 va[4], vb[4];
#pragma unroll
    for (int i = 0; i < 4; ++i) {
      int cid = tid + 256 * i;          // 0..1023
      int row = cid >> 3, slot = cid & 7;
      va[i] = *(const short8*)(xb + (size_t)(m0 + row) * KPAD + k0 + slot * 8);
      vb[i] = *(const short8*)(wb + (size_t)(n0 + row) * KPAD + k0 + slot * 8);
    }
    __syncthreads();   // previous iteration's LDS reads complete
#pragma unroll
    for (int i = 0; i < 4; ++i) {
      int cid = tid + 256 * i;
      int row = cid >> 3, slot = cid & 7;
      int sw = (slot ^ (row & 7)) * 8;
      *(short8*)(&Asm[row * 64 + sw]) = va[i];
      *(short8*)(&Bsm[row * 64 + sw]) = vb[i];
    }
    __syncthreads();
#pragma unroll
    for (int kk = 0; kk < 2; ++kk) {
      int ks = (l >> 4) + kk * 4;
      short8 af[4], bfr[4];
#pragma unroll
      for (int mt = 0; mt < 4; ++mt) {
        int row = wr + mt * 16 + (l & 15);
        af[mt] = *(const short8*)(&Asm[row * 64 + ((ks ^ (row & 7)) * 8)]);
      }
#pragma unroll
      for (int nt = 0; nt < 4; ++nt) {
        int row = wc + nt * 16 + (l & 15);
        bfr[nt] = *(const short8*)(&Bsm[row * 64 + ((ks ^ (row & 7)) * 8)]);
      }
#pragma unroll
      for (int mt = 0; mt < 4; ++mt)
#pragma unroll
        for (int nt = 0; nt < 4; ++nt)
          acc[mt][nt] = __builtin_amdgcn_mfma_f32_16x16x32_bf16(af[mt], bfr[nt], acc[mt][nt], 0, 0, 0);
    }
  }
  // epilogue: + bias, store bf16
#pragma unroll
  for (int nt = 0; nt < 4; ++nt) {
    int n = n0 + wc + nt * 16 + (l & 15);
    float bv = bias[n];
#pragma unroll
    for (int mt = 0; mt < 4; ++mt) {
      int rbase = m0 + wr + mt * 16 + ((l >> 4) * 4);
#pragma unroll
      for (int r = 0; r < 4; ++r)
        xproj[(size_t)(rbase + r) * 2048 + n] = f2bf(acc[mt][nt][r] + bv);
    }
  }
}

// ---------------------------------------------------------------- recurrent LSTM
// grid 128 = (batch 64) x (dir 2); block 256 threads; thread j owns hidden unit j.
__global__ __launch_bounds__(256) void k_rec(const ushort* __restrict__ xproj,
                                             const uint4* __restrict__ whh8,
                                             ushort* __restrict__ hcat) {
  const int blk = blockIdx.x;
  const int b = blk >> 1, dir = blk & 1;
  const int j = threadIdx.x;
  __shared__ __align__(16) float hbuf[HID];
  hbuf[j] = 0.f;
  float c = 0.f;
  const uint4* W = whh8 + (size_t)dir * 32 * 1024;
  const ushort* xp0 = xproj + (size_t)dir * 1024 + j;
  __syncthreads();

  for (int t = 0; t < SEQ; ++t) {
    int tt = dir ? (SEQ - 1 - t) : t;
    size_t m = (size_t)b * SEQ + tt;
    const ushort* xp = xp0 + m * 2048;
    float z0 = bf2f(xp[0]);
    float z1 = bf2f(xp[256]);
    float z2 = bf2f(xp[512]);
    float z3 = bf2f(xp[768]);
#pragma unroll 4
    for (int k8 = 0; k8 < 32; ++k8) {
      const float4* hp = (const float4*)&hbuf[k8 * 8];
      float4 h0 = hp[0], h1 = hp[1];
      const uint4* wp = W + k8 * 1024 + j;
      uint4 w0 = wp[0], w1 = wp[256], w2 = wp[512], w3 = wp[768];
      z0 += h0.x*blo(w0.x) + h0.y*bhi(w0.x) + h0.z*blo(w0.y) + h0.w*bhi(w0.y)
          + h1.x*blo(w0.z) + h1.y*bhi(w0.z) + h1.z*blo(w0.w) + h1.w*bhi(w0.w);
      z1 += h0.x*blo(w1.x) + h0.y*bhi(w1.x) + h0.z*blo(w1.y) + h0.w*bhi(w1.y)
          + h1.x*blo(w1.z) + h1.y*bhi(w1.z) + h1.z*blo(w1.w) + h1.w*bhi(w1.w);
      z2 += h0.x*blo(w2.x) + h0.y*bhi(w2.x) + h0.z*blo(w2.y) + h0.w*bhi(w2.y)
          + h1.x*blo(w2.z) + h1.y*bhi(w2.z) + h1.z*blo(w2.w) + h1.w*bhi(w2.w);
      z3 += h0.x*blo(w3.x) + h0.y*bhi(w3.x) + h0.z*blo(w3.y) + h0.w*bhi(w3.y)
          + h1.x*blo(w3.z) + h1.y*bhi(w3.z) + h1.z*blo(w3.w) + h1.w*bhi(w3.w);
    }
    float ig = 1.f / (1.f + __expf(-z0));
    float fg = 1.f / (1.f + __expf(-z1));
    float gg = tanhf(z2);
    float og = 1.f / (1.f + __expf(-z3));
    c = fg * c + ig * gg;
    float h = og * tanhf(c);
    hcat[m * 512 + dir * 256 + j] = f2bf(h);
    __syncthreads();          // all reads of old h done
    hbuf[j] = h;
    __syncthreads();          // new h visible
  }
}

// ---------------------------------------------------------------- output linear
// logits[m, j] = sum_k hcat[m,k] * wlt[k,j] + b_lin[j]
__global__ __launch_bounds__(256) void k_lin(const ushort* __restrict__ hcat,
                                             const ushort* __restrict__ wltb,
                                             const float* __restrict__ blin,
                                             float* __restrict__ logits) {
  __shared__ __align__(16) ushort wsm[512 * 64];
  const int tid = threadIdx.x;
#pragma unroll
  for (int i = 0; i < 16; ++i)
    ((short8*)wsm)[tid + 256 * i] = ((const short8*)wltb)[tid + 256 * i];
  __syncthreads();
  const int w = tid >> 6, l = tid & 63;
  float blv = (l < NTAG) ? blin[l] : 0.f;
  for (int q = 0; q < 4; ++q) {
    size_t m = (size_t)blockIdx.x * 16 + w * 4 + q;
    const ushort* hp = hcat + m * 512;
    float acc = blv;
#pragma unroll 2
    for (int k8 = 0; k8 < 64; ++k8) {
      short8 hv = *(const short8*)(hp + k8 * 8);
#pragma unroll
      for (int kk = 0; kk < 8; ++kk)
        acc += bf2f((ushort)hv[kk]) * bf2f(wsm[(k8 * 8 + kk) * 64 + l]);
    }
    if (l < NTAG) logits[m * NTAG + l] = acc;
  }
}

// ---------------------------------------------------------------- CRF
// one wave per chain; lane = tag (48 active). alpha kept in log2 units.
__global__ __launch_bounds__(64) void k_crf(const float* __restrict__ logits,
                                            const int* __restrict__ labels,
                                            const int* __restrict__ slen,
                                            const float* __restrict__ trans,
                                            const float* __restrict__ startt,
                                            const float* __restrict__ endt,
                                            const float* __restrict__ T2Tg,
                                            const float* __restrict__ cm2g,
                                            float* __restrict__ out) {
  __shared__ float Ttab[NTAG * NTAG];
  __shared__ __align__(16) float T2T[NTAG * T2STRIDE];
  __shared__ __align__(16) float As[64];
  __shared__ float cm2[NTAG];
  const int b = blockIdx.x, l = threadIdx.x;
  for (int i = l; i < NTAG * NTAG; i += 64) Ttab[i] = trans[i];
  for (int i = l; i < NTAG * T2STRIDE; i += 64) T2T[i] = T2Tg[i];
  if (l < NTAG) cm2[l] = cm2g[l];
  __syncthreads();
  const float L2E = 1.4426950408889634f;
  const float LN2 = 0.6931471805599453f;
  int len = slen[b]; len = (len < 1) ? 1 : (len > SEQ ? SEQ : len);
  float A = -3.0e38f;
  float score = 0.f;
  int prevtag = 0, lasttag = 0;
  float myend = (l < NTAG) ? endt[l] : 0.f;
  float cmv   = (l < NTAG) ? cm2[l] : 0.f;

  for (int t = 0; t < SEQ; ++t) {
    const float* lg = logits + ((size_t)b * SEQ + t) * NTAG;
    float lv = (l < NTAG) ? lg[l] : -3.0e38f;
    float mx = lv;
#pragma unroll
    for (int s = 32; s; s >>= 1) mx = fmaxf(mx, __shfl_xor(mx, s));
    float e = (l < NTAG) ? exp2f((lv - mx) * L2E) : 0.f;
    float ssum = e;
#pragma unroll
    for (int s = 32; s; s >>= 1) ssum += __shfl_xor(ssum, s);
    float p = e / ssum;                           // softmax prob (linear)
    int tag = labels[(size_t)b * SEQ + t];
    float ptag = __shfl(p, tag);
    if (t == 0) {
      A = (l < NTAG) ? (startt[l] + p) * L2E : -3.0e38f;
      score = startt[tag] + ptag;
      prevtag = tag; lasttag = tag;
    } else if (t < len) {
      float amax = (l < NTAG) ? A : -3.0e38f;
#pragma unroll
      for (int s = 32; s; s >>= 1) amax = fmaxf(amax, __shfl_xor(amax, s));
      As[l] = A - amax;
      __syncthreads();
      if (l < NTAG) {
        float acc2 = 0.f;
#pragma unroll 3
        for (int ic = 0; ic < 12; ++ic) {
          float4 av = *(const float4*)&As[ic * 4];
          float4 tv = *(const float4*)&T2T[l * T2STRIDE + ic * 4];
          acc2 += exp2f(av.x + tv.x);
          acc2 += exp2f(av.y + tv.y);
          acc2 += exp2f(av.z + tv.z);
          acc2 += exp2f(av.w + tv.w);
        }
        A = amax + cmv + log2f(acc2) + p * L2E;
      }
      __syncthreads();
      score += Ttab[prevtag * NTAG + tag] + ptag;
      prevtag = tag; lasttag = tag;
    }
  }
  score += endt[lasttag];
  float v = (l < NTAG) ? (A + myend * L2E) : -3.0e38f;
  float M = v;
#pragma unroll
  for (int s = 32; s; s >>= 1) M = fmaxf(M, __shfl_xor(M, s));
  float sz = (l < NTAG) ? exp2f(v - M) : 0.f;
#pragma unroll
  for (int s = 32; s; s >>= 1) sz += __shfl_xor(sz, s);
  float logz = (M + log2f(sz)) * LN2;
  if (l == 0) atomicAdd(out, logz - score);
}

// ---------------------------------------------------------------- launch
extern "C" void kernel_launch(void* const* d_in, const int* in_sizes, int n_in,
                              void* d_out, int out_size, void* d_ws, size_t ws_size,
                              hipStream_t stream) {
  const int*   tok    = (const int*)d_in[0];
  const int*   slen   = (const int*)d_in[1];
  const int*   lab    = (const int*)d_in[2];
  const float* emb    = (const float*)d_in[3];
  const float* wihf   = (const float*)d_in[4];
  const float* whhf   = (const float*)d_in[5];
  const float* bihf   = (const float*)d_in[6];
  const float* bhhf   = (const float*)d_in[7];
  const float* wihb   = (const float*)d_in[8];
  const float* whhb   = (const float*)d_in[9];
  const float* bihb   = (const float*)d_in[10];
  const float* bhhb   = (const float*)d_in[11];
  const float* wlin   = (const float*)d_in[12];
  const float* blin   = (const float*)d_in[13];
  const float* trans  = (const float*)d_in[14];
  const float* startt = (const float*)d_in[15];
  const float* endt   = (const float*)d_in[16];
  float* out = (float*)d_out;

  char* p = (char*)d_ws;
  ushort* xproj = (ushort*)p; p += (size_t)NTOK * 2048 * 2;   // 134 MB
  ushort* xb    = (ushort*)p; p += (size_t)NTOK * KPAD * 2;   // 21 MB
  ushort* wb    = (ushort*)p; p += (size_t)2048 * KPAD * 2;   // 1.3 MB
  uint4*  whh8  = (uint4*)p;  p += (size_t)2 * 32 * 1024 * 16; // 1 MB
  ushort* hcat  = (ushort*)p; p += (size_t)NTOK * 512 * 2;    // 33.5 MB
  float*  logit = (float*)p;  p += (size_t)NTOK * NTAG * 4;   // 6.3 MB
  ushort* wltb  = (ushort*)p; p += (size_t)32768 * 2;         // 64 KB
  float*  bias  = (float*)p;  p += 2048 * 4;
  float*  T2Tg  = (float*)p;  p += (size_t)NTAG * T2STRIDE * 4;
  float*  cm2g  = (float*)p;  p += 256;

  k_prep_wb  <<<2048, 320, 0, stream>>>(wihf, wihb, wb);
  k_prep_whh <<<64, 256, 0, stream>>>(whhf, whhb, whh8);
  k_prep_wlt <<<128, 256, 0, stream>>>(wlin, wltb);
  k_prep_small<<<1, 256, 0, stream>>>(bihf, bhhf, bihb, bhhb, trans, bias, T2Tg, cm2g, out);
  k_gather   <<<NTOK / 4, 256, 0, stream>>>(tok, emb, xb);
  k_gemm     <<<dim3(16, 256), 256, 0, stream>>>(xb, wb, bias, xproj);
  k_rec      <<<128, 256, 0, stream>>>(xproj, whh8, hcat);
  k_lin      <<<NTOK / 16, 256, 0, stream>>>(hcat, wltb, blin, logit);
  k_crf      <<<BATCH, 64, 0, stream>>>(logit, lab, slen, trans, startt, endt, T2Tg, cm2g, out);
}

// Round 2
// 3929.778 us; speedup vs baseline: 1.4390x; 1.4390x over previous
//
#include <hip/hip_runtime.h>

// ---------------------------------------------------------------------------
// BiLSTM-CRF fused pipeline for MI355X (gfx950)
// B=64, S=512, V=50000, E=300, H=256 (H2=512), T=48
//   k_gather   : x = emb[token_ids]  -> bf16, K padded 300->320
//   k_gemm     : xproj = x @ [W_ih_f;W_ih_b]^T + bias   (bf16 MFMA, 128x128 tile)
//   k_rec      : 32 blocks = (NH=4 hidden-split) x (GB=4 batch-split) x 2 dirs.
//                W_hh register-resident (128 VGPR/wave of MFMA B-frags).
//                Per-step h exchange via MALL (agent-scope atomics) + flag sync.
//   k_lin      : logits = [h_f,h_b] @ W_lin^T + b_lin
//   k_crf      : per-chain wave, lane=tag; softmax fused; log2-domain scan
// ---------------------------------------------------------------------------

using short8 = __attribute__((ext_vector_type(8))) short;
using f32x4  = __attribute__((ext_vector_type(4))) float;
typedef unsigned int  uint;
typedef unsigned short ushort;
typedef unsigned long long ull;

#define BATCH 64
#define SEQ   512
#define EMB   300
#define KPAD  320
#define HID   256
#define NTAG  48
#define NTOK  (BATCH*SEQ)          // 32768
#define T2STRIDE 60

__device__ __forceinline__ float bf2f(ushort u) { return __uint_as_float(((uint)u) << 16); }
__device__ __forceinline__ ushort f2bf(float f) {
  uint u = __float_as_uint(f);
  return (ushort)((u + 0x7fffu + ((u >> 16) & 1u)) >> 16);   // RNE
}
__device__ __forceinline__ uint pk2(float a, float b) {
  return (uint)f2bf(a) | ((uint)f2bf(b) << 16);
}

// ---------------------------------------------------------------- prep kernels
__global__ void k_prep_wb(const float* __restrict__ wihf, const float* __restrict__ wihb,
                          ushort* __restrict__ wb) {
  int n = blockIdx.x;            // 0..2047
  int k = threadIdx.x;           // 0..319
  float v = 0.f;
  if (k < EMB) v = (n < 1024) ? wihf[n * EMB + k] : wihb[(n - 1024) * EMB + k];
  wb[n * KPAD + k] = f2bf(v);
}

// W_hh MFMA B-fragments: entry (dir, nh, w, g, kt, lane) -> 8 bf16 (uint4)
//   unit = nh*64 + w*16 + (lane&15); k = kt*32 + (lane>>4)*8 + j
//   value = W_dir[(g*256+unit)*256 + k]
__global__ void k_prep_wfrag(const float* __restrict__ whhf, const float* __restrict__ whhb,
                             uint4* __restrict__ wfrag) {
  int flat = blockIdx.x * 256 + threadIdx.x;     // < 65536
  int l  = flat & 63;
  int kt = (flat >> 6) & 7;
  int g  = (flat >> 9) & 3;
  int w  = (flat >> 11) & 3;
  int nh = (flat >> 13) & 3;
  int dir = flat >> 15;
  const float* W = dir ? whhb : whhf;
  int unit = nh * 64 + w * 16 + (l & 15);
  int k0 = kt * 32 + (l >> 4) * 8;
  const float* wr = W + (size_t)(g * 256 + unit) * 256 + k0;
  uint4 o;
  o.x = pk2(wr[0], wr[1]); o.y = pk2(wr[2], wr[3]);
  o.z = pk2(wr[4], wr[5]); o.w = pk2(wr[6], wr[7]);
  wfrag[flat] = o;
}

__global__ void k_prep_wlt(const float* __restrict__ wlin, ushort* __restrict__ wltb) {
  int idx = blockIdx.x * 256 + threadIdx.x;   // < 32768
  int k = idx >> 6, j = idx & 63;
  wltb[idx] = f2bf((j < NTAG) ? wlin[j * 512 + k] : 0.f);
}

__global__ void k_prep_small(const float* __restrict__ bihf, const float* __restrict__ bhhf,
                             const float* __restrict__ bihb, const float* __restrict__ bhhb,
                             const float* __restrict__ trans,
                             float* __restrict__ bias, float* __restrict__ T2Tg,
                             float* __restrict__ cm2g, uint* __restrict__ flags,
                             float* __restrict__ out) {
  int tid = threadIdx.x;
  if (tid == 0) out[0] = 0.f;
  flags[tid] = 0u;                       // 256 flag words (8 groups x 32)
  for (int i = tid; i < 2048; i += 256)
    bias[i] = (i < 1024) ? (bihf[i] + bhhf[i]) : (bihb[i - 1024] + bhhb[i - 1024]);
  if (tid < NTAG) {
    const float L2E = 1.4426950408889634f;
    float cm = -3.0e38f;
    for (int i = 0; i < NTAG; ++i) cm = fmaxf(cm, trans[i * NTAG + tid] * L2E);
    cm2g[tid] = cm;
    for (int i = 0; i < NTAG; ++i)
      T2Tg[tid * T2STRIDE + i] = trans[i * NTAG + tid] * L2E - cm;
  }
}

// ---------------------------------------------------------------- gather
__global__ __launch_bounds__(256) void k_gather(const int* __restrict__ tok,
                                                const float* __restrict__ emb,
                                                ushort* __restrict__ xb) {
  int r = blockIdx.x * 4 + (threadIdx.x >> 6);   // token row, < 32768
  int l = threadIdx.x & 63;
  int t = tok[r];
  const float* e = emb + (size_t)t * EMB;
  ushort* xr = xb + (size_t)r * KPAD;
#pragma unroll
  for (int q = 0; q < 5; ++q) {
    int k = l + q * 64;
    xr[k] = f2bf((k < EMB) ? e[k] : 0.f);
  }
}

// ---------------------------------------------------------------- input-proj GEMM
__global__ __launch_bounds__(256) void k_gemm(const ushort* __restrict__ xb,
                                              const ushort* __restrict__ wb,
                                              const float* __restrict__ bias,
                                              ushort* __restrict__ xproj) {
  __shared__ __align__(16) ushort Asm[128 * 64];
  __shared__ __align__(16) ushort Bsm[128 * 64];
  const int tid = threadIdx.x;
  const int w = tid >> 6, l = tid & 63;
  const int m0 = blockIdx.y * 128, n0 = blockIdx.x * 128;
  const int wr = (w >> 1) * 64, wc = (w & 1) * 64;
  f32x4 acc[4][4] = {};

  for (int kt = 0; kt < 5; ++kt) {
    const int k0 = kt * 64;
    short8 va[4], vb[4];
#pragma unroll
    for (int i = 0; i < 4; ++i) {
      int cid = tid + 256 * i;
      int row = cid >> 3, slot = cid & 7;
      va[i] = *(const short8*)(xb + (size_t)(m0 + row) * KPAD + k0 + slot * 8);
      vb[i] = *(const short8*)(wb + (size_t)(n0 + row) * KPAD + k0 + slot * 8);
    }
    __syncthreads();
#pragma unroll
    for (int i = 0; i < 4; ++i) {
      int cid = tid + 256 * i;
      int row = cid >> 3, slot = cid & 7;
      int sw = (slot ^ (row & 7)) * 8;
      *(short8*)(&Asm[row * 64 + sw]) = va[i];
      *(short8*)(&Bsm[row * 64 + sw]) = vb[i];
    }
    __syncthreads();
#pragma unroll
    for (int kk = 0; kk < 2; ++kk) {
      int ks = (l >> 4) + kk * 4;
      short8 af[4], bfr[4];
#pragma unroll
      for (int mt = 0; mt < 4; ++mt) {
        int row = wr + mt * 16 + (l & 15);
        af[mt] = *(const short8*)(&Asm[row * 64 + ((ks ^ (row & 7)) * 8)]);
      }
#pragma unroll
      for (int nt = 0; nt < 4; ++nt) {
        int row = wc + nt * 16 + (l & 15);
        bfr[nt] = *(const short8*)(&Bsm[row * 64 + ((ks ^ (row & 7)) * 8)]);
      }
#pragma unroll
      for (int mt = 0; mt < 4; ++mt)
#pragma unroll
        for (int nt = 0; nt < 4; ++nt)
          acc[mt][nt] = __builtin_amdgcn_mfma_f32_16x16x32_bf16(af[mt], bfr[nt], acc[mt][nt], 0, 0, 0);
    }
  }
#pragma unroll
  for (int nt = 0; nt < 4; ++nt) {
    int n = n0 + wc + nt * 16 + (l & 15);
    float bv = bias[n];
#pragma unroll
    for (int mt = 0; mt < 4; ++mt) {
      int rbase = m0 + wr + mt * 16 + ((l >> 4) * 4);
#pragma unroll
      for (int r = 0; r < 4; ++r)
        xproj[(size_t)(rbase + r) * 2048 + n] = f2bf(acc[mt][nt][r] + bv);
    }
  }
}

// ---------------------------------------------------------------- recurrent LSTM
// 32 blocks: blk = nh*8 + dir*4 + gb  (group {nh=0..3} shares one XCD slot)
// wave w owns hidden units [nh*64+w*16, +16) x 4 gates, batch chunk [gb*16,+16)
__global__ __launch_bounds__(256) void k_rec(const ushort* __restrict__ xproj,
                                             const uint4* __restrict__ wfrag,
                                             ushort* __restrict__ hcat,
                                             uint* __restrict__ hx,
                                             uint* __restrict__ flags) {
  const int blk = blockIdx.x;
  const int nh = blk >> 3, dir = (blk >> 2) & 1, gb = blk & 3;
  const int tid = threadIdx.x, w = tid >> 6, l = tid & 63;
  const int grp = dir * 4 + gb;
  uint* flag = flags + grp * 32;
  const int unit = nh * 64 + w * 16 + (l & 15);
  const int bb = gb * 16;
  const int rowq = (l >> 4) * 4;          // batch-local row base in acc
  // ---- weights -> registers (128 VGPR/wave), once
  short8 wreg[4][8];
  {
    const uint4* wp = wfrag + (size_t)(dir * 16 + nh * 4 + w) * 2048 + l;
#pragma unroll
    for (int g = 0; g < 4; ++g)
#pragma unroll
      for (int kt = 0; kt < 8; ++kt) {
        union { uint4 u; short8 s; } cvt;
        cvt.u = wp[g * 512 + kt * 64];
        wreg[g][kt] = cvt.s;
      }
  }
  float c[4] = {0.f, 0.f, 0.f, 0.f};
  const uint hxbase0 = (uint)grp * 4096u;  // [grp][parity][16][128] uints
  int guard = 0;

  for (int t = 0; t < SEQ; ++t) {
    const int tt = dir ? (SEQ - 1 - t) : t;
    // xproj loads issued before the spin (independent of h)
    float xpv[4][4];
#pragma unroll
    for (int r = 0; r < 4; ++r) {
      const size_t m = (size_t)(bb + rowq + r) * SEQ + tt;
      const ushort* xp = xproj + m * 2048 + dir * 1024 + unit;
      xpv[r][0] = bf2f(xp[0]);
      xpv[r][1] = bf2f(xp[256]);
      xpv[r][2] = bf2f(xp[512]);
      xpv[r][3] = bf2f(xp[768]);
    }
    f32x4 acc[4] = {};
    if (t > 0) {
      if (tid == 0) {
        const uint tgt = 4u * (uint)t;
        while (__hip_atomic_load(flag, __ATOMIC_RELAXED, __HIP_MEMORY_SCOPE_AGENT) < tgt) {
          __builtin_amdgcn_s_sleep(2);
          if (++guard > (1 << 21)) break;   // fail-fast, never hang
        }
        (void)__hip_atomic_load(flag, __ATOMIC_ACQUIRE, __HIP_MEMORY_SCOPE_AGENT);
      }
      __syncthreads();
      const uint rbase = hxbase0 + (((t - 1) & 1) ? 2048u : 0u) + (uint)(l & 15) * 128u;
      short8 af[8];
#pragma unroll
      for (int kt = 0; kt < 8; ++kt) {
        const ull* p = (const ull*)(hx + rbase + (uint)(kt * 32 + (l >> 4) * 8) / 2u);
        union { ull u[2]; short8 s; } cc;
        cc.u[0] = __hip_atomic_load(p,     __ATOMIC_RELAXED, __HIP_MEMORY_SCOPE_AGENT);
        cc.u[1] = __hip_atomic_load(p + 1, __ATOMIC_RELAXED, __HIP_MEMORY_SCOPE_AGENT);
        af[kt] = cc.s;
      }
#pragma unroll
      for (int g = 0; g < 4; ++g)
#pragma unroll
        for (int kt = 0; kt < 8; ++kt)
          acc[g] = __builtin_amdgcn_mfma_f32_16x16x32_bf16(af[kt], wreg[g][kt], acc[g], 0, 0, 0);
    }
    const uint wbase = hxbase0 + ((t & 1) ? 2048u : 0u);
#pragma unroll
    for (int r = 0; r < 4; ++r) {
      const size_t m = (size_t)(bb + rowq + r) * SEQ + tt;
      float zi = acc[0][r] + xpv[r][0];
      float zf = acc[1][r] + xpv[r][1];
      float zg = acc[2][r] + xpv[r][2];
      float zo = acc[3][r] + xpv[r][3];
      float ig = 1.f / (1.f + __expf(-zi));
      float fg = 1.f / (1.f + __expf(-zf));
      float gg = 2.f / (1.f + __expf(-2.f * zg)) - 1.f;
      float og = 1.f / (1.f + __expf(-zo));
      c[r] = fg * c[r] + ig * gg;
      float hv = og * (2.f / (1.f + __expf(-2.f * c[r])) - 1.f);
      hcat[m * 512 + dir * 256 + unit] = f2bf(hv);
      float hn = __shfl_xor(hv, 1);
      if (!(l & 1))
        __hip_atomic_store(hx + wbase + (uint)(rowq + r) * 128u + (uint)(unit >> 1),
                           pk2(hv, hn), __ATOMIC_RELAXED, __HIP_MEMORY_SCOPE_AGENT);
    }
    __syncthreads();
    if (tid == 0)
      __hip_atomic_fetch_add(flag, 1u, __ATOMIC_RELEASE, __HIP_MEMORY_SCOPE_AGENT);
  }
}

// ---------------------------------------------------------------- output linear
__global__ __launch_bounds__(256) void k_lin(const ushort* __restrict__ hcat,
                                             const ushort* __restrict__ wltb,
                                             const float* __restrict__ blin,
                                             float* __restrict__ logits) {
  __shared__ __align__(16) ushort wsm[512 * 64];
  const int tid = threadIdx.x;
#pragma unroll
  for (int i = 0; i < 16; ++i)
    ((short8*)wsm)[tid + 256 * i] = ((const short8*)wltb)[tid + 256 * i];
  __syncthreads();
  const int w = tid >> 6, l = tid & 63;
  float blv = (l < NTAG) ? blin[l] : 0.f;
  for (int q = 0; q < 4; ++q) {
    size_t m = (size_t)blockIdx.x * 16 + w * 4 + q;
    const ushort* hp = hcat + m * 512;
    float acc = blv;
#pragma unroll 2
    for (int k8 = 0; k8 < 64; ++k8) {
      short8 hv = *(const short8*)(hp + k8 * 8);
#pragma unroll
      for (int kk = 0; kk < 8; ++kk)
        acc += bf2f((ushort)hv[kk]) * bf2f(wsm[(k8 * 8 + kk) * 64 + l]);
    }
    if (l < NTAG) logits[m * NTAG + l] = acc;
  }
}

// ---------------------------------------------------------------- CRF
__global__ __launch_bounds__(64) void k_crf(const float* __restrict__ logits,
                                            const int* __restrict__ labels,
                                            const int* __restrict__ slen,
                                            const float* __restrict__ trans,
                                            const float* __restrict__ startt,
                                            const float* __restrict__ endt,
                                            const float* __restrict__ T2Tg,
                                            const float* __restrict__ cm2g,
                                            float* __restrict__ out) {
  __shared__ float Ttab[NTAG * NTAG];
  __shared__ __align__(16) float T2T[NTAG * T2STRIDE];
  __shared__ __align__(16) float As[64];
  __shared__ float cm2[NTAG];
  const int b = blockIdx.x, l = threadIdx.x;
  for (int i = l; i < NTAG * NTAG; i += 64) Ttab[i] = trans[i];
  for (int i = l; i < NTAG * T2STRIDE; i += 64) T2T[i] = T2Tg[i];
  if (l < NTAG) cm2[l] = cm2g[l];
  __syncthreads();
  const float L2E = 1.4426950408889634f;
  const float LN2 = 0.6931471805599453f;
  int len = slen[b]; len = (len < 1) ? 1 : (len > SEQ ? SEQ : len);
  float A = -3.0e38f;
  float score = 0.f;
  int prevtag = 0, lasttag = 0;
  float myend = (l < NTAG) ? endt[l] : 0.f;
  float cmv   = (l < NTAG) ? cm2[l] : 0.f;

  for (int t = 0; t < SEQ; ++t) {
    const float* lg = logits + ((size_t)b * SEQ + t) * NTAG;
    float lv = (l < NTAG) ? lg[l] : -3.0e38f;
    float mx = lv;
#pragma unroll
    for (int s = 32; s; s >>= 1) mx = fmaxf(mx, __shfl_xor(mx, s));
    float e = (l < NTAG) ? exp2f((lv - mx) * L2E) : 0.f;
    float ssum = e;
#pragma unroll
    for (int s = 32; s; s >>= 1) ssum += __shfl_xor(ssum, s);
    float p = e / ssum;
    int tag = labels[(size_t)b * SEQ + t];
    float ptag = __shfl(p, tag);
    if (t == 0) {
      A = (l < NTAG) ? (startt[l] + p) * L2E : -3.0e38f;
      score = startt[tag] + ptag;
      prevtag = tag; lasttag = tag;
    } else if (t < len) {
      float amax = (l < NTAG) ? A : -3.0e38f;
#pragma unroll
      for (int s = 32; s; s >>= 1) amax = fmaxf(amax, __shfl_xor(amax, s));
      As[l] = A - amax;
      __syncthreads();
      if (l < NTAG) {
        float acc2 = 0.f;
#pragma unroll 3
        for (int ic = 0; ic < 12; ++ic) {
          float4 av = *(const float4*)&As[ic * 4];
          float4 tv = *(const float4*)&T2T[l * T2STRIDE + ic * 4];
          acc2 += exp2f(av.x + tv.x);
          acc2 += exp2f(av.y + tv.y);
          acc2 += exp2f(av.z + tv.z);
          acc2 += exp2f(av.w + tv.w);
        }
        A = amax + cmv + log2f(acc2) + p * L2E;
      }
      __syncthreads();
      score += Ttab[prevtag * NTAG + tag] + ptag;
      prevtag = tag; lasttag = tag;
    }
  }
  score += endt[lasttag];
  float v = (l < NTAG) ? (A + myend * L2E) : -3.0e38f;
  float M = v;
#pragma unroll
  for (int s = 32; s; s >>= 1) M = fmaxf(M, __shfl_xor(M, s));
  float sz = (l < NTAG) ? exp2f(v - M) : 0.f;
#pragma unroll
  for (int s = 32; s; s >>= 1) sz += __shfl_xor(sz, s);
  float logz = (M + log2f(sz)) * LN2;
  if (l == 0) atomicAdd(out, logz - score);
}

// ---------------------------------------------------------------- launch
extern "C" void kernel_launch(void* const* d_in, const int* in_sizes, int n_in,
                              void* d_out, int out_size, void* d_ws, size_t ws_size,
                              hipStream_t stream) {
  const int*   tok    = (const int*)d_in[0];
  const int*   slen   = (const int*)d_in[1];
  const int*   lab    = (const int*)d_in[2];
  const float* emb    = (const float*)d_in[3];
  const float* wihf   = (const float*)d_in[4];
  const float* whhf   = (const float*)d_in[5];
  const float* bihf   = (const float*)d_in[6];
  const float* bhhf   = (const float*)d_in[7];
  const float* wihb   = (const float*)d_in[8];
  const float* whhb   = (const float*)d_in[9];
  const float* bihb   = (const float*)d_in[10];
  const float* bhhb   = (const float*)d_in[11];
  const float* wlin   = (const float*)d_in[12];
  const float* blin   = (const float*)d_in[13];
  const float* trans  = (const float*)d_in[14];
  const float* startt = (const float*)d_in[15];
  const float* endt   = (const float*)d_in[16];
  float* out = (float*)d_out;

  char* p = (char*)d_ws;
  ushort* xproj = (ushort*)p; p += (size_t)NTOK * 2048 * 2;     // 134 MB
  ushort* xb    = (ushort*)p; p += (size_t)NTOK * KPAD * 2;     // 21 MB
  ushort* wb    = (ushort*)p; p += (size_t)2048 * KPAD * 2;     // 1.3 MB
  uint4*  wfrag = (uint4*)p;  p += (size_t)65536 * 16;          // 1 MB
  ushort* hcat  = (ushort*)p; p += (size_t)NTOK * 512 * 2;      // 33.5 MB
  float*  logit = (float*)p;  p += (size_t)NTOK * NTAG * 4;     // 6.3 MB
  ushort* wltb  = (ushort*)p; p += (size_t)32768 * 2;           // 64 KB
  float*  bias  = (float*)p;  p += 2048 * 4;
  float*  T2Tg  = (float*)p;  p += (size_t)NTAG * T2STRIDE * 4;
  float*  cm2g  = (float*)p;  p += 256;
  uint*   hx    = (uint*)p;   p += (size_t)32768 * 4;           // 128 KB h exchange
  uint*   flags = (uint*)p;   p += 256 * 4;                     // 8 groups x 32

  k_prep_wb   <<<2048, 320, 0, stream>>>(wihf, wihb, wb);
  k_prep_wfrag<<<256, 256, 0, stream>>>(whhf, whhb, wfrag);
  k_prep_wlt  <<<128, 256, 0, stream>>>(wlin, wltb);
  k_prep_small<<<1, 256, 0, stream>>>(bihf, bhhf, bihb, bhhb, trans, bias, T2Tg, cm2g, flags, out);
  k_gather    <<<NTOK / 4, 256, 0, stream>>>(tok, emb, xb);
  k_gemm      <<<dim3(16, 256), 256, 0, stream>>>(xb, wb, bias, xproj);
  k_rec       <<<32, 256, 0, stream>>>(xproj, wfrag, hcat, hx, flags);
  k_lin       <<<NTOK / 16, 256, 0, stream>>>(hcat, wltb, blin, logit);
  k_crf       <<<BATCH, 64, 0, stream>>>(logit, lab, slen, trans, startt, endt, T2Tg, cm2g, out);
}